// Round 2
// baseline (2024.170 us; speedup 1.0000x reference)
//
#include <hip/hip_runtime.h>

// FPS (farthest point sampling) + gather for B=16, N=65536, S=512, C=64.
// Decomposition: 16 WGs per batch, each owns a 4096-pt chunk in REGISTERS
// (16 pts/thread x 3 floats). Cross-WG argmax per iteration via RELAXED
// device-scope slots in d_ws (double-buffered by parity, iteration-tagged).
//
// Round-1 protocol: checksummed 3-dword slots, NO atomic RMWs.
//   lo  = (it << 16) | idx      (16-bit tag, 16-bit index)
//   hi  = dist fp32 bits
//   chk = lo + hi               (u32 wraparound checksum)
// Every 32-bit agent-scope atomic store/load is single-copy atomic on the
// cross-XCD path (dwords cannot tear; only 64-bit dwordx2 accesses could,
// which was the round-0 divergence). The poller pins generation `it` via the
// tag in `lo`, then validates hi against chk:
//   - chk fresh + hi stale passing requires hi_old == hi_new  -> benign
//   - chk stale + hi stale passing requires lo_old == lo_new  -> impossible
//     (tags differ), so any cross-generation mix fails -> retry.
// Double-buffer safety: a WG writes generation it+2 into a parity slot only
// after observing every WG's it+1 publish, which is strictly after all their
// generation-it reads completed (unchanged invariant).
//
// This removes the round-0 fetch_or polling (every poll was an exclusive RMW
// at the LLC: ~260us regression, 1531 -> 1790us). Publish is fire-and-forget
// stores; poll is concurrent loads.
//
// Slot layout: dword base = ((wg*2 + parity)*NB + b) * 4. For fixed
// (parity,b) consecutive wg are 512B apart -> the 16 slots one batch polls
// live in 16 different 64B lines. Total 8 KiB of d_ws.

#define NB   16
#define NPTS 65536
#define NS   512
#define WPB  16                 // workgroups per batch
#define CHUNK (NPTS / WPB)      // 4096 points per WG
#define NTHR 256
#define PPT  (CHUNK / NTHR)     // 16 points per thread
#define NWAVE (NTHR / 64)       // 4 waves per WG
#define SPW  (NS / WPB)         // 32 samples gathered per WG

#define SLOTD(parity, b, wg) \
    ((((size_t)(wg) * 2 + (size_t)(parity)) * NB + (size_t)(b)) * 4)

__device__ __forceinline__ unsigned ld_rlx(const unsigned* p) {
    return __hip_atomic_load(p, __ATOMIC_RELAXED, __HIP_MEMORY_SCOPE_AGENT);
}
__device__ __forceinline__ void st_rlx(unsigned* p, unsigned v) {
    __hip_atomic_store(p, v, __ATOMIC_RELAXED, __HIP_MEMORY_SCOPE_AGENT);
}

// Exact fp32, reference op order, no FMA contraction:
__device__ __forceinline__ float sqdist3(float x, float y, float z,
                                         float cx, float cy, float cz) {
    float dx = __fsub_rn(x, cx);
    float dy = __fsub_rn(y, cy);
    float dz = __fsub_rn(z, cz);
    return __fadd_rn(__fadd_rn(__fmul_rn(dx, dx), __fmul_rn(dy, dy)),
                     __fmul_rn(dz, dz));
}

__global__ void __launch_bounds__(NTHR, 1)
fps_kernel(const float* __restrict__ xyz, const float* __restrict__ feat,
           float* __restrict__ out, unsigned* __restrict__ slots) {
    const int wg   = blockIdx.x & (WPB - 1);
    const int b    = blockIdx.x / WPB;
    const int tid  = threadIdx.x;
    const int lane = tid & 63;
    const int wave = tid >> 6;

    __shared__ int   sel[NS];      // selected indices (for the final gather)
    __shared__ float cent[3];      // current centroid
    __shared__ float wbd[NWAVE];
    __shared__ int   wbi[NWAVE];

    const float* bx  = xyz + (size_t)b * NPTS * 3;
    const int   base = wg * CHUNK;

    // One-time chunk load global -> registers (SoA in regs, 64 VGPRs).
    float rx[PPT], ry[PPT], rz[PPT], dmin[PPT];
#pragma unroll
    for (int k = 0; k < PPT; ++k) {
        int g = base + tid + k * NTHR;
        rx[k] = bx[3 * g + 0];
        ry[k] = bx[3 * g + 1];
        rz[k] = bx[3 * g + 2];
        dmin[k] = 1e10f;                              // reference BIG
    }

    if (tid == 0) {
        sel[0] = 0;                                   // seed point 0
        cent[0] = bx[0]; cent[1] = bx[1]; cent[2] = bx[2];
    }
    __syncthreads();

    for (int it = 1; it < NS; ++it) {
        const float cx = cent[0], cy = cent[1], cz = cent[2];
        float bd = -1.0f; int bi = 0;
#pragma unroll
        for (int k = 0; k < PPT; ++k) {
            float d  = sqdist3(rx[k], ry[k], rz[k], cx, cy, cz);
            float dm = fminf(dmin[k], d);
            dmin[k] = dm;
            if (dm > bd) { bd = dm; bi = base + tid + k * NTHR; } // strict > keeps min idx
        }
        // wave reduction: max dist, tie -> min global index
        for (int off = 32; off >= 1; off >>= 1) {
            float od = __shfl_down(bd, off, 64);
            int   oi = __shfl_down(bi, off, 64);
            if (od > bd || (od == bd && oi < bi)) { bd = od; bi = oi; }
        }
        if (lane == 0) { wbd[wave] = bd; wbi[wave] = bi; }
        __syncthreads();
        if (tid == 0) {
            for (int w = 1; w < NWAVE; ++w) {
                float od = wbd[w]; int oi = wbi[w];
                if (od > bd || (od == bd && oi < bi)) { bd = od; bi = oi; }
            }
            unsigned lo = ((unsigned)it << 16) | (unsigned)bi;
            unsigned hi = __float_as_uint(bd);
            unsigned* sp = slots + SLOTD(it & 1, b, wg);
            // hi/chk first, tag last (reduces retry probability; soundness
            // does not depend on store order).
            st_rlx(sp + 1, hi);
            st_rlx(sp + 2, lo + hi);
            st_rlx(sp + 0, lo);
        }
        // all-to-all: 16 lanes of wave 0 spin on the batch's 16 slots
        if (wave == 0 && lane < WPB) {
            unsigned* sp = slots + SLOTD(it & 1, b, lane);
            unsigned lo, hi, chk;
            for (;;) {
                lo = ld_rlx(sp + 0);
                if ((lo >> 16) == (unsigned)it) break;
                __builtin_amdgcn_s_sleep(1);
            }
            hi  = ld_rlx(sp + 1);
            chk = ld_rlx(sp + 2);
            while (lo + hi != chk) {                   // cross-generation mix
                __builtin_amdgcn_s_sleep(1);
                hi  = ld_rlx(sp + 1);
                chk = ld_rlx(sp + 2);
            }
            float d2 = __uint_as_float(hi);
            int   i2 = (int)(lo & 0xFFFFu);
            // prefetch THIS candidate's coords (overlaps with the reduce)
            float px = bx[3 * i2 + 0];
            float py = bx[3 * i2 + 1];
            float pz = bx[3 * i2 + 2];
            int   wl = lane;                          // winning lane tracker
            for (int off = 8; off >= 1; off >>= 1) {
                float od = __shfl_down(d2, off, 64);
                int   oi = __shfl_down(i2, off, 64);
                int   ol = __shfl_down(wl, off, 64);
                if (lane + off < WPB) {
                    if (od > d2 || (od == d2 && oi < i2)) {
                        d2 = od; i2 = oi; wl = ol;
                    }
                }
            }
            int w = __shfl(wl, 0, 64);                // winner lane, broadcast
            float wxc = __shfl(px, w, 64);
            float wyc = __shfl(py, w, 64);
            float wzc = __shfl(pz, w, 64);
            if (lane == 0) {
                sel[it] = i2;
                cent[0] = wxc; cent[1] = wyc; cent[2] = wzc;
            }
        }
        __syncthreads();
    }

    // Gather: this WG writes samples [wg*32, wg*32+32).
    const float* bf   = feat + (size_t)b * NPTS * 64;
    float*       oxyz = out + (size_t)b * NS * 3;
    float*       of   = out + (size_t)NB * NS * 3 + (size_t)b * NS * 64;
    const int c  = tid & 63;
    const int sr = tid >> 6;                          // 0..3
    for (int k = 0; k < SPW / NWAVE; ++k) {
        int s = wg * SPW + k * NWAVE + sr;
        int p = sel[s];
        of[(size_t)s * 64 + c] = bf[(size_t)p * 64 + c];
    }
    if (tid < SPW * 3) {
        int s    = wg * SPW + tid / 3;
        int comp = tid % 3;
        oxyz[s * 3 + comp] = bx[sel[s] * 3 + comp];
    }
}

extern "C" void kernel_launch(void* const* d_in, const int* in_sizes, int n_in,
                              void* d_out, int out_size, void* d_ws, size_t ws_size,
                              hipStream_t stream) {
    const float* xyz = (const float*)d_in[0];
    const float* f   = (const float*)d_in[1];
    float* out = (float*)d_out;
    unsigned* slots = (unsigned*)d_ws;
    // Clear iteration tags (ws is poisoned 0xAA; tag 0xAAAA never matches,
    // but tag 0 can never match it>=1 either -> memset to 0).
    hipMemsetAsync(d_ws, 0,
                   (size_t)2 * NB * WPB * 4 * sizeof(unsigned), stream);
    fps_kernel<<<dim3(NB * WPB), dim3(NTHR), 0, stream>>>(xyz, f, out, slots);
}

// Round 4
// 1888.054 us; speedup vs baseline: 1.0721x; 1.0721x over previous
//
#include <hip/hip_runtime.h>

// FPS (farthest point sampling) + gather for B=16, N=65536, S=512, C=64.
// 16 WGs per batch, each owns a 4096-pt chunk in REGISTERS (16 pts/thread).
// Cross-WG argmax per iteration via RELAXED agent-scope slots in d_ws.
//
// (Round 3 = round 2 resubmitted verbatim: the round-3 bench died to an
// infra/container failure before running; audit found no hang risk.)
//
// Round-2 lesson: rounds 1 & 2 both cost ~1790us because the poll DETECT
// path had one extra dependent LLC round trip vs the original racy kernel
// (RMW latency in r1; lo-spin -> dependent hi/chk loads in r2). Fix: single
// round-trip poll with two SELF-TAGGED dwords loaded in parallel:
//   wA = (it16 << 16) | idx16
//   wB = dist_bits | genbit << 31     (dist = squared L2 >= 0 -> sign free)
// Each dword is single-copy atomic (only 64-bit dwordx2 could tear - the
// round-0 bug). Each is individually generation-pinned, so no cross-word
// mix can be accepted. genbit = (it>>1)&1 distinguishes it from it-2; values
// older than it-2 cannot reappear (per-location coherence: this same poller
// lane already observed the it-2 store to this address, and the publisher
// thread's stores to it are program-ordered). Init: parity-1 wB region
// (first use it=1, want genbit 0) memset 0x80 -> blocks; parity-0 region
// (first use it=2, want genbit 1) memset 0x00 -> blocks.
//
// Publisher path shortened: 64 sub-slots per batch (one per WAVE). Each
// wave's lane 0 publishes its wave-local argmax right after the in-wave
// shuffle reduce - no LDS hand-off, no barrier, no serial 4-way reduce.
// Wave 0 polls all 64 sub-slots (one per lane, 256B contiguous = one
// coalesced load) and reduces with a 6-step shuffle. Self-synchronizing:
// wave 0 cannot pass its poll until its own waves 1-3 published, which is
// after they read the previous centroid -> ONE __syncthreads per iteration
// (centroid broadcast) instead of two. Wave 0 additionally keeps the new
// centroid in registers (post-shuffle) so its next compute needs no LDS read.

#define NB    16
#define NPTS  65536
#define NS    512
#define WPB   16                 // workgroups per batch
#define CHUNK (NPTS / WPB)       // 4096 points per WG
#define NTHR  256
#define PPT   (CHUNK / NTHR)     // 16 points per thread
#define NWAVE (NTHR / 64)        // 4 waves per WG
#define SPW   (NS / WPB)         // 32 samples gathered per WG
#define NSLOT (WPB * NWAVE)      // 64 sub-slots per batch (one per wave)

__device__ __forceinline__ unsigned ld_rlx(const unsigned* p) {
    return __hip_atomic_load(p, __ATOMIC_RELAXED, __HIP_MEMORY_SCOPE_AGENT);
}
__device__ __forceinline__ void st_rlx(unsigned* p, unsigned v) {
    __hip_atomic_store(p, v, __ATOMIC_RELAXED, __HIP_MEMORY_SCOPE_AGENT);
}

// Exact fp32, reference op order, no FMA contraction:
__device__ __forceinline__ float sqdist3(float x, float y, float z,
                                         float cx, float cy, float cz) {
    float dx = __fsub_rn(x, cx);
    float dy = __fsub_rn(y, cy);
    float dz = __fsub_rn(z, cz);
    return __fadd_rn(__fadd_rn(__fmul_rn(dx, dx), __fmul_rn(dy, dy)),
                     __fmul_rn(dz, dz));
}

__global__ void __launch_bounds__(NTHR, 1)
fps_kernel(const float* __restrict__ xyz, const float* __restrict__ feat,
           float* __restrict__ out, unsigned* __restrict__ ws) {
    const int wg   = blockIdx.x & (WPB - 1);
    const int b    = blockIdx.x / WPB;
    const int tid  = threadIdx.x;
    const int lane = tid & 63;
    const int wave = tid >> 6;

    unsigned* wA = ws;                        // 2 * NB * NSLOT dwords (8 KiB)
    unsigned* wB = ws + 2 * NB * NSLOT;       // 8 KiB

    __shared__ int   sel[NS];      // selected indices (for the final gather)
    __shared__ float cent[3];      // current centroid (for waves 1..3)

    const float* bx  = xyz + (size_t)b * NPTS * 3;
    const int   base = wg * CHUNK;

    // One-time chunk load global -> registers (SoA in regs).
    float rx[PPT], ry[PPT], rz[PPT], dmin[PPT];
#pragma unroll
    for (int k = 0; k < PPT; ++k) {
        int g = base + tid + k * NTHR;
        rx[k] = bx[3 * g + 0];
        ry[k] = bx[3 * g + 1];
        rz[k] = bx[3 * g + 2];
        dmin[k] = 1e10f;                              // reference BIG
    }

    // Seed point 0. Wave 0 keeps the centroid in registers.
    float ncx = bx[0], ncy = bx[1], ncz = bx[2];
    if (tid == 0) {
        sel[0] = 0;
        cent[0] = ncx; cent[1] = ncy; cent[2] = ncz;
    }
    __syncthreads();

    for (int it = 1; it < NS; ++it) {
        float cx, cy, cz;
        if (wave == 0) { cx = ncx;     cy = ncy;     cz = ncz;     }
        else           { cx = cent[0]; cy = cent[1]; cz = cent[2]; }

        float bd = -1.0f; int bi = 0;
#pragma unroll
        for (int k = 0; k < PPT; ++k) {
            float d  = sqdist3(rx[k], ry[k], rz[k], cx, cy, cz);
            float dm = fminf(dmin[k], d);
            dmin[k] = dm;
            if (dm > bd) { bd = dm; bi = base + tid + k * NTHR; } // strict > keeps min idx
        }
        // wave reduction: max dist, tie -> min global index
        for (int off = 32; off >= 1; off >>= 1) {
            float od = __shfl_down(bd, off, 64);
            int   oi = __shfl_down(bi, off, 64);
            if (od > bd || (od == bd && oi < bi)) { bd = od; bi = oi; }
        }
        // each wave's lane 0 publishes its wave-local argmax directly
        const size_t sb = ((size_t)(it & 1) * NB + b) * NSLOT;
        const unsigned gbit = (((unsigned)it >> 1) & 1u) << 31;
        if (lane == 0) {
            size_t s = sb + (size_t)(wg * NWAVE + wave);
            st_rlx(wB + s, __float_as_uint(bd) | gbit);   // B first, A (tag) last
            st_rlx(wA + s, ((unsigned)it << 16) | (unsigned)bi);
        }

        if (wave == 0) {
            // all 64 lanes poll one sub-slot each; both loads in flight
            // together -> single round-trip detect.
            const unsigned wantTag = (unsigned)it;
            unsigned a, bv;
            for (;;) {
                a  = ld_rlx(wA + sb + lane);
                bv = ld_rlx(wB + sb + lane);
                if ((a >> 16) == wantTag && (bv & 0x80000000u) == gbit) break;
                __builtin_amdgcn_s_sleep(1);
            }
            float d2 = __uint_as_float(bv & 0x7FFFFFFFu);
            int   i2 = (int)(a & 0xFFFFu);
            // prefetch THIS candidate's coords (overlaps with the reduce)
            float px = bx[3 * i2 + 0];
            float py = bx[3 * i2 + 1];
            float pz = bx[3 * i2 + 2];
            int   wl = lane;                          // winning lane tracker
            for (int off = 32; off >= 1; off >>= 1) {
                float od = __shfl_down(d2, off, 64);
                int   oi = __shfl_down(i2, off, 64);
                int   ol = __shfl_down(wl, off, 64);
                if (lane + off < 64) {
                    if (od > d2 || (od == d2 && oi < i2)) {
                        d2 = od; i2 = oi; wl = ol;
                    }
                }
            }
            int w = __shfl(wl, 0, 64);                // winner lane, broadcast
            ncx = __shfl(px, w, 64);
            ncy = __shfl(py, w, 64);
            ncz = __shfl(pz, w, 64);
            if (lane == 0) {
                sel[it] = i2;                         // lane 0 holds winner
                cent[0] = ncx; cent[1] = ncy; cent[2] = ncz;
            }
        }
        __syncthreads();   // release new centroid to waves 1..3
    }

    // Gather: this WG writes samples [wg*32, wg*32+32).
    const float* bf   = feat + (size_t)b * NPTS * 64;
    float*       oxyz = out + (size_t)b * NS * 3;
    float*       of   = out + (size_t)NB * NS * 3 + (size_t)b * NS * 64;
    const int c  = tid & 63;
    const int sr = tid >> 6;                          // 0..3
    for (int k = 0; k < SPW / NWAVE; ++k) {
        int s = wg * SPW + k * NWAVE + sr;
        int p = sel[s];
        of[(size_t)s * 64 + c] = bf[(size_t)p * 64 + c];
    }
    if (tid < SPW * 3) {
        int s    = wg * SPW + tid / 3;
        int comp = tid % 3;
        oxyz[s * 3 + comp] = bx[sel[s] * 3 + comp];
    }
}

extern "C" void kernel_launch(void* const* d_in, const int* in_sizes, int n_in,
                              void* d_out, int out_size, void* d_ws, size_t ws_size,
                              hipStream_t stream) {
    const float* xyz = (const float*)d_in[0];
    const float* f   = (const float*)d_in[1];
    float* out = (float*)d_out;
    unsigned* ws = (unsigned*)d_ws;
    // wA (both parities): tag 0 never matches it>=1.
    hipMemsetAsync(ws, 0x00, (size_t)2 * NB * NSLOT * 4, stream);
    // wB parity 0 (first use it=2 wants genbit 1): init genbit 0.
    hipMemsetAsync(ws + 2 * NB * NSLOT, 0x00, (size_t)NB * NSLOT * 4, stream);
    // wB parity 1 (first use it=1 wants genbit 0): init genbit 1.
    hipMemsetAsync(ws + 3 * NB * NSLOT, 0x80, (size_t)NB * NSLOT * 4, stream);
    fps_kernel<<<dim3(NB * WPB), dim3(NTHR), 0, stream>>>(xyz, f, out, ws);
}